// Round 6
// baseline (2304.713 us; speedup 1.0000x reference)
//
#include <hip/hip_runtime.h>

#define T_LEN 2048
#define NTHREADS 448   // 7 waves: 7 groups (3 gx-layers + 4 gh-layers) x 64 gates

// Diagonal-wavefront fused 4-layer GRU, fp32, weights register-resident.
// Block b = batch row b. Superstep s: layer l computes timestep t = s - l.
//
// Thread map (tid 0..447):
//   g = tid>>6 in 0..6 : 0..2 = gx-dots for layer g+1 (input = h[g])
//                        3..6 = gh-dots for layer g-3 (input = h[g-3])
//   c = tid&63         : gate column 0..63
// Each thread owns FULL dot rows {c, 64+c, 128+c} = 192 weight floats in VGPRs.
//
// KEY: static 84KB __shared__ (not extern). The register-budget heuristic uses
// compile-time LDS to bound blocks/CU: extern shared reads as 0 -> compiler
// assumes multi-block occupancy -> 112-reg cap -> pinned weights spill to
// AGPRs -> 192 v_accvgpr_read per superstep (rounds 4/5, 2.3 ms). Static 84KB
// forces 1 block/CU -> 2 waves/SIMD -> 256-reg budget -> demand (~232) fits.
__global__ __launch_bounds__(NTHREADS)
void gru_fused(const float* __restrict__ x,
               const float* __restrict__ w_ih0,
               const float* __restrict__ w_ih_rest,
               const float* __restrict__ w_hh,
               const float* __restrict__ b_ih,
               const float* __restrict__ b_hh,
               const float* __restrict__ fc_w,
               const float* __restrict__ fc_b,
               float* __restrict__ out)
{
    // static LDS: 21504 floats = 84 KiB -> exactly 1 block/CU (160KB pool)
    __shared__ float smem[21504];
    float* xs   = smem;                    // 8192: x row as float4[2048]
    float* hst  = xs + 8192;               // 256:  h state per layer
    float* gbuf = hst + 256;               // 1344: 7*192 raw dot results
    float* w0s  = gbuf + 1344;             // 768:  layer-0 W_ih rows
    float* bihs = w0s + 768;               // 768:  b_ih (all 4 layers)
    float* bhhs = bihs + 768;              // 768:  b_hh (all 4 layers)

    const int tid = threadIdx.x;
    const int b   = blockIdx.x;

    // ---- stage x row, layer-0 weights, biases; zero h ----
    {
        const float4* xg = (const float4*)(x + (size_t)b * (T_LEN * 4));
        float4* xd = (float4*)xs;
        for (int i = tid; i < T_LEN; i += NTHREADS) xd[i] = xg[i];
    }
    for (int i = tid; i < 192; i += NTHREADS) ((float4*)w0s)[i]  = ((const float4*)w_ih0)[i];
    for (int i = tid; i < 192; i += NTHREADS) ((float4*)bihs)[i] = ((const float4*)b_ih)[i];
    for (int i = tid; i < 192; i += NTHREADS) ((float4*)bhhs)[i] = ((const float4*)b_hh)[i];
    if (tid < 256) hst[tid] = 0.0f;

    // ---- dot-thread identity ----
    const int g = tid >> 6;                  // 0..6
    const int c = tid & 63;                  // 0..63
    const int src = (g < 3) ? g : (g - 3);

    // ---- preload dot weights into registers (float4[3][16] = 192 VGPRs) ----
    float4 w4[3][16];
    {
        const float* wsrc = (g < 3) ? (w_ih_rest + g * (192 * 64))
                                    : (w_hh      + (g - 3) * (192 * 64));
        #pragma unroll
        for (int i = 0; i < 3; ++i) {
            const float4* p = (const float4*)(wsrc + (i * 64 + c) * 64);
            #pragma unroll
            for (int q = 0; q < 16; ++q) w4[i][q] = p[q];
        }
    }
    // Pin every weight in a VGPR: asm defs are not rematerializable.
    #pragma unroll
    for (int i = 0; i < 3; ++i)
        #pragma unroll
        for (int q = 0; q < 16; ++q)
            asm volatile("" : "+v"(w4[i][q].x), "+v"(w4[i][q].y),
                             "+v"(w4[i][q].z), "+v"(w4[i][q].w));

    const int cl = tid >> 6;      // combine identity (tid<256): layer
    const int cc = tid & 63;      // gate
    __syncthreads();

    const float4* vb4 = (const float4*)(hst + src * 64);

    // ---- main diagonal loop ----
    for (int s = 0; s < T_LEN + 3; ++s) {
        // dot phase: 192 FMAs per thread as 6 independent 32-FMA chains
        // (two k-halves per row, summed once -> round-5 numerics, 1e-7 absmax)
        float a0 = 0.f, a1 = 0.f, a2 = 0.f;   // k = 0..31
        float b0 = 0.f, b1 = 0.f, b2 = 0.f;   // k = 32..63
        #pragma unroll
        for (int q = 0; q < 8; ++q) {
            const float4 f = vb4[q];
            a0 = fmaf(f.x, w4[0][q].x, a0); a0 = fmaf(f.y, w4[0][q].y, a0);
            a0 = fmaf(f.z, w4[0][q].z, a0); a0 = fmaf(f.w, w4[0][q].w, a0);
            a1 = fmaf(f.x, w4[1][q].x, a1); a1 = fmaf(f.y, w4[1][q].y, a1);
            a1 = fmaf(f.z, w4[1][q].z, a1); a1 = fmaf(f.w, w4[1][q].w, a1);
            a2 = fmaf(f.x, w4[2][q].x, a2); a2 = fmaf(f.y, w4[2][q].y, a2);
            a2 = fmaf(f.z, w4[2][q].z, a2); a2 = fmaf(f.w, w4[2][q].w, a2);
        }
        #pragma unroll
        for (int q = 8; q < 16; ++q) {
            const float4 f = vb4[q];
            b0 = fmaf(f.x, w4[0][q].x, b0); b0 = fmaf(f.y, w4[0][q].y, b0);
            b0 = fmaf(f.z, w4[0][q].z, b0); b0 = fmaf(f.w, w4[0][q].w, b0);
            b1 = fmaf(f.x, w4[1][q].x, b1); b1 = fmaf(f.y, w4[1][q].y, b1);
            b1 = fmaf(f.z, w4[1][q].z, b1); b1 = fmaf(f.w, w4[1][q].w, b1);
            b2 = fmaf(f.x, w4[2][q].x, b2); b2 = fmaf(f.y, w4[2][q].y, b2);
            b2 = fmaf(f.z, w4[2][q].z, b2); b2 = fmaf(f.w, w4[2][q].w, b2);
        }
        gbuf[g * 192 +       c] = a0 + b0;
        gbuf[g * 192 +  64 + c] = a1 + b1;
        gbuf[g * 192 + 128 + c] = a2 + b2;
        __syncthreads();

        // combine phase: 4 waves, one gate each, layer cl at t = s - cl
        if (tid < 256) {
            const int t = s - cl;
            if (t >= 0 && t < T_LEN) {
                float xr, xz, xn;
                if (cl == 0) {
                    const float4 xv = ((const float4*)xs)[t];
                    const float4 u0 = ((const float4*)w0s)[cc];
                    const float4 u1 = ((const float4*)w0s)[64 + cc];
                    const float4 u2 = ((const float4*)w0s)[128 + cc];
                    xr = bihs[cc]       + xv.x * u0.x + xv.y * u0.y + xv.z * u0.z + xv.w * u0.w;
                    xz = bihs[64 + cc]  + xv.x * u1.x + xv.y * u1.y + xv.z * u1.z + xv.w * u1.w;
                    xn = bihs[128 + cc] + xv.x * u2.x + xv.y * u2.y + xv.z * u2.z + xv.w * u2.w;
                } else {
                    xr = bihs[cl * 192 +       cc] + gbuf[(cl - 1) * 192 +       cc];
                    xz = bihs[cl * 192 +  64 + cc] + gbuf[(cl - 1) * 192 +  64 + cc];
                    xn = bihs[cl * 192 + 128 + cc] + gbuf[(cl - 1) * 192 + 128 + cc];
                }
                const float hr = bhhs[cl * 192 +       cc] + gbuf[(3 + cl) * 192 +       cc];
                const float hz = bhhs[cl * 192 +  64 + cc] + gbuf[(3 + cl) * 192 +  64 + cc];
                const float hn = bhhs[cl * 192 + 128 + cc] + gbuf[(3 + cl) * 192 + 128 + cc];
                const float hold = hst[cl * 64 + cc];

                const float r = 1.0f / (1.0f + __expf(-(xr + hr)));
                const float z = 1.0f / (1.0f + __expf(-(xz + hz)));
                const float e = __expf(2.0f * (xn + r * hn));
                const float n = 1.0f - 2.0f / (e + 1.0f);   // tanh
                hst[cl * 64 + cc] = n + z * (hold - n);      // (1-z)*n + z*h
            }
        }
        __syncthreads();
    }

    // ---- fused FC head on layer-3 final h ----
    if (tid < 5) {
        float acc = fc_b[tid];
        const float* wf = fc_w + tid * 64;
        #pragma unroll
        for (int k = 0; k < 64; ++k) acc = fmaf(hst[3 * 64 + k], wf[k], acc);
        out[(size_t)b * 5 + tid] = acc;
    }
}

extern "C" void kernel_launch(void* const* d_in, const int* in_sizes, int n_in,
                              void* d_out, int out_size, void* d_ws, size_t ws_size,
                              hipStream_t stream) {
    const float* x         = (const float*)d_in[0];
    const float* w_ih0     = (const float*)d_in[1];
    const float* w_ih_rest = (const float*)d_in[2];
    const float* w_hh      = (const float*)d_in[3];
    const float* b_ih      = (const float*)d_in[4];
    const float* b_hh      = (const float*)d_in[5];
    const float* fc_w      = (const float*)d_in[6];
    const float* fc_b      = (const float*)d_in[7];

    gru_fused<<<dim3(256), dim3(NTHREADS), 0, stream>>>(
        x, w_ih0, w_ih_rest, w_hh, b_ih, b_hh, fc_w, fc_b, (float*)d_out);
}

// Round 7
// 2021.142 us; speedup vs baseline: 1.1403x; 1.1403x over previous
//
#include <hip/hip_runtime.h>

#define T_LEN 2048
#define NTHREADS 896   // 14 waves: 7 groups (3 gx-layers + 4 gh-layers) x 64 gates x 2 k-halves

// Diagonal-wavefront fused 4-layer GRU, fp32.
// Block b = batch row b. Superstep s: layer l computes timestep t = s - l.
//
// Thread map (tid 0..895):
//   g2 = tid>>7 in 0..6 : 0..2 = gx-dots for layer g2+1 (input = h[g2])
//                         3..6 = gh-dots for layer g2-3 (input = h[g2-3])
//   c  = (tid&127)>>1   : gate column 0..63
//   half = tid&1        : k-half (32 of 64)
// Each thread owns half-rows of {c, 64+c, 128+c} = 96 weight floats.
//
// DISCRIMINATING EXPERIMENT (r7 = r3 + static LDS, single variable):
// r3 (896thr, waves_per_eu(4,4), extern LDS) -> budget 64. If the RA budget
// is LDS-aware, static 84KB forces 1 WG/CU -> 14 waves -> 4/SIMD -> budget
// 128 >= demand (~120) -> weights fully arch-VGPR-resident -> ~1.1 ms.
// If budget stays 64, the hard "2 WG/CU" model is confirmed and round 8
// goes to the 2-CU-per-row split design.
__global__ __launch_bounds__(NTHREADS)
__attribute__((amdgpu_waves_per_eu(4, 4)))
void gru_fused(const float* __restrict__ x,
               const float* __restrict__ w_ih0,
               const float* __restrict__ w_ih_rest,
               const float* __restrict__ w_hh,
               const float* __restrict__ b_ih,
               const float* __restrict__ b_hh,
               const float* __restrict__ fc_w,
               const float* __restrict__ fc_b,
               float* __restrict__ out)
{
    // static LDS: 21504 floats = 84 KiB -> at most 1 block/CU (160KB pool)
    __shared__ float smem[21504];
    float* xs   = smem;                    // 8192: x row as float4[2048]
    float* hst  = xs + 8192;               // 256:  h state per layer
    float* gbuf = hst + 256;               // 1344: 7*192 raw dot results
    float* w0s  = gbuf + 1344;             // 768:  layer-0 W_ih rows
    float* bihs = w0s + 768;               // 768:  b_ih (all 4 layers)
    float* bhhs = bihs + 768;              // 768:  b_hh (all 4 layers)

    const int tid = threadIdx.x;
    const int b   = blockIdx.x;

    // ---- stage x row, layer-0 weights, biases; zero h ----
    {
        const float4* xg = (const float4*)(x + (size_t)b * (T_LEN * 4));
        float4* xd = (float4*)xs;
        for (int i = tid; i < T_LEN; i += NTHREADS) xd[i] = xg[i];
    }
    if (tid < 192)                ((float4*)w0s)[tid]        = ((const float4*)w_ih0)[tid];
    else if (tid < 384)           ((float4*)bihs)[tid - 192] = ((const float4*)b_ih)[tid - 192];
    else if (tid < 576)           ((float4*)bhhs)[tid - 384] = ((const float4*)b_hh)[tid - 384];
    if (tid < 256) hst[tid] = 0.0f;

    // ---- dot-thread identity ----
    const int g2   = tid >> 7;                  // 0..6
    const int r7_  = tid & 127;
    const int c    = r7_ >> 1;                  // 0..63
    const int half = r7_ & 1;                   // 0/1
    const int src  = (g2 < 3) ? g2 : (g2 - 3);

    // ---- preload dot weights into registers (float4[3][8] = 96 VGPRs) ----
    float4 w4[3][8];
    {
        const float* wsrc = (g2 < 3) ? (w_ih_rest + g2 * (192 * 64))
                                     : (w_hh      + (g2 - 3) * (192 * 64));
        #pragma unroll
        for (int i = 0; i < 3; ++i) {
            const float4* p = (const float4*)(wsrc + (i * 64 + c) * 64 + half * 32);
            #pragma unroll
            for (int q = 0; q < 8; ++q) w4[i][q] = p[q];
        }
    }
    // Pin weights: asm defs are not rematerializable (no in-loop reloads).
    #pragma unroll
    for (int i = 0; i < 3; ++i)
        #pragma unroll
        for (int q = 0; q < 8; ++q)
            asm volatile("" : "+v"(w4[i][q].x), "+v"(w4[i][q].y),
                             "+v"(w4[i][q].z), "+v"(w4[i][q].w));

    const int cl = tid >> 6;      // combine identity (tid<256): layer
    const int cc = tid & 63;      // gate
    __syncthreads();

    const float4* vb4 = (const float4*)(hst + src * 64 + half * 32);

    // ---- main diagonal loop ----
    for (int s = 0; s < T_LEN + 3; ++s) {
        // dot phase: 96 FMAs per thread (3 chains), h broadcast from LDS
        float a0 = 0.f, a1 = 0.f, a2 = 0.f;
        #pragma unroll
        for (int q = 0; q < 8; ++q) {
            const float4 f = vb4[q];
            a0 = fmaf(f.x, w4[0][q].x, a0); a0 = fmaf(f.y, w4[0][q].y, a0);
            a0 = fmaf(f.z, w4[0][q].z, a0); a0 = fmaf(f.w, w4[0][q].w, a0);
            a1 = fmaf(f.x, w4[1][q].x, a1); a1 = fmaf(f.y, w4[1][q].y, a1);
            a1 = fmaf(f.z, w4[1][q].z, a1); a1 = fmaf(f.w, w4[1][q].w, a1);
            a2 = fmaf(f.x, w4[2][q].x, a2); a2 = fmaf(f.y, w4[2][q].y, a2);
            a2 = fmaf(f.z, w4[2][q].z, a2); a2 = fmaf(f.w, w4[2][q].w, a2);
        }
        a0 += __shfl_xor(a0, 1);
        a1 += __shfl_xor(a1, 1);
        a2 += __shfl_xor(a2, 1);
        if (half == 0) {
            gbuf[g2 * 192 +       c] = a0;
            gbuf[g2 * 192 +  64 + c] = a1;
            gbuf[g2 * 192 + 128 + c] = a2;
        }
        __syncthreads();

        // combine phase: 4 waves, one gate each, layer cl at t = s - cl
        if (tid < 256) {
            const int t = s - cl;
            if (t >= 0 && t < T_LEN) {
                float xr, xz, xn;
                if (cl == 0) {
                    const float4 xv = ((const float4*)xs)[t];
                    const float4 u0 = ((const float4*)w0s)[cc];
                    const float4 u1 = ((const float4*)w0s)[64 + cc];
                    const float4 u2 = ((const float4*)w0s)[128 + cc];
                    xr = bihs[cc]       + xv.x * u0.x + xv.y * u0.y + xv.z * u0.z + xv.w * u0.w;
                    xz = bihs[64 + cc]  + xv.x * u1.x + xv.y * u1.y + xv.z * u1.z + xv.w * u1.w;
                    xn = bihs[128 + cc] + xv.x * u2.x + xv.y * u2.y + xv.z * u2.z + xv.w * u2.w;
                } else {
                    xr = bihs[cl * 192 +       cc] + gbuf[(cl - 1) * 192 +       cc];
                    xz = bihs[cl * 192 +  64 + cc] + gbuf[(cl - 1) * 192 +  64 + cc];
                    xn = bihs[cl * 192 + 128 + cc] + gbuf[(cl - 1) * 192 + 128 + cc];
                }
                const float hr = bhhs[cl * 192 +       cc] + gbuf[(3 + cl) * 192 +       cc];
                const float hz = bhhs[cl * 192 +  64 + cc] + gbuf[(3 + cl) * 192 +  64 + cc];
                const float hn = bhhs[cl * 192 + 128 + cc] + gbuf[(3 + cl) * 192 + 128 + cc];
                const float hold = hst[cl * 64 + cc];

                const float r = 1.0f / (1.0f + __expf(-(xr + hr)));
                const float z = 1.0f / (1.0f + __expf(-(xz + hz)));
                const float e = __expf(2.0f * (xn + r * hn));
                const float n = 1.0f - 2.0f / (e + 1.0f);   // tanh
                hst[cl * 64 + cc] = n + z * (hold - n);      // (1-z)*n + z*h
            }
        }
        __syncthreads();
    }

    // ---- fused FC head on layer-3 final h ----
    if (tid < 5) {
        float acc = fc_b[tid];
        const float* wf = fc_w + tid * 64;
        #pragma unroll
        for (int k = 0; k < 64; ++k) acc = fmaf(hst[3 * 64 + k], wf[k], acc);
        out[(size_t)b * 5 + tid] = acc;
    }
}

extern "C" void kernel_launch(void* const* d_in, const int* in_sizes, int n_in,
                              void* d_out, int out_size, void* d_ws, size_t ws_size,
                              hipStream_t stream) {
    const float* x         = (const float*)d_in[0];
    const float* w_ih0     = (const float*)d_in[1];
    const float* w_ih_rest = (const float*)d_in[2];
    const float* w_hh      = (const float*)d_in[3];
    const float* b_ih      = (const float*)d_in[4];
    const float* b_hh      = (const float*)d_in[5];
    const float* fc_w      = (const float*)d_in[6];
    const float* fc_b      = (const float*)d_in[7];

    gru_fused<<<dim3(256), dim3(NTHREADS), 0, stream>>>(
        x, w_ih0, w_ih_rest, w_hh, b_ih, b_hh, fc_w, fc_b, (float*)d_out);
}